// Round 21
// baseline (213.077 us; speedup 1.0000x reference)
//
#include <hip/hip_runtime.h>
#include <hip/hip_bf16.h>
#include <math.h>

// Problem constants
#define N_ROT 32      // 8 inclinations x 4 azimuths
#define O_CH 16
#define I_CH 8
#define KVOL 27
#define DHW 40
#define SPATIAL (DHW*DHW*DHW)        // 64000
#define OUT_PLANE (2*O_CH*SPATIAL)   // 2048000 elements per output tensor
#define PDHW 42
#define PSPAT (PDHW*PDHW*PDHW)       // 74088
#define WROT_ELEMS (O_CH*KVOL*I_CH*N_ROT)   // 110592 f32
#define XPAD_ELEMS (2*PSPAT*I_CH)           // 1185408 f32 (NDHWC padded)
// split-bf16 screen error ~3e-5 worst-case realistic; margin = 2e-3 (>>10x)
#define MARGIN 2.0e-3f
#define WORK_CAP 2048000
// padded LDS x-tile geometry (16B px units): py stride 11, pz stride 110
#define PYS 11
#define PZS 110

typedef __attribute__((ext_vector_type(8))) short bf16x8;
typedef __attribute__((ext_vector_type(4))) float f32x4;

__device__ __forceinline__ ushort f2bf(float v) {
    union { __hip_bfloat16 h; ushort u; } cv;
    cv.h = __float2bfloat16(v);      // RNE
    return cv.u;
}
__device__ __forceinline__ float bf2f(ushort u) {
    union { unsigned u32; float f; } cv;
    cv.u32 = ((unsigned)u) << 16;
    return cv.f;
}

// ---------------------------------------------------------------------------
// Kernel 1: rotated weights, parallelized over (o, r, p) — verified in R20.
// Per-(o,i,r,p) contraction chain UNCHANGED from passing R4-R20 kernels
// (bit pattern load-bearing).
// ---------------------------------------------------------------------------
template<bool FULL>
__global__ void build_wrot(const float* __restrict__ w, float* __restrict__ wrot,
                           float* __restrict__ wrotT, ushort* __restrict__ wbf_hi,
                           ushort* __restrict__ wbf_lo, int* __restrict__ gcount) {
    int tid = blockIdx.x * blockDim.x + threadIdx.x;
    if (FULL && tid == 0) *gcount = 0;
    if (tid >= N_ROT * KVOL * O_CH) return;
    int o  = tid / (N_ROT * KVOL);
    int rp = tid % (N_ROT * KVOL);
    int r = rp / KVOL, p = rp % KVOL;
    int th = r / 4, ph = r % 4;
    double theta = ((double)th * 22.5) * (M_PI / 180.0);   // np.deg2rad
    double phi   = ((double)ph * 90.0) * (M_PI / 180.0);
    double ct = cos(theta), st = sin(theta);
    double cp = cos(phi),   sp = sin(phi);
    double R00 = cp*ct, R01 = -sp, R02 = cp*st;
    double R10 = sp*ct, R11 =  cp, R12 = sp*st;
    double R20 = -st,   R21 = 0.0, R22 = ct;
    double d0 = (double)(p / 9) - 1.0;
    double d1 = (double)((p / 3) % 3) - 1.0;
    double d2 = (double)(p % 3) - 1.0;
    double s0 = d0*R00 + d1*R10 + d2*R20 + 1.0;
    double s1 = d0*R01 + d1*R11 + d2*R21 + 1.0;
    double s2 = d0*R02 + d1*R12 + d2*R22 + 1.0;
    double f0 = floor(s0), f1 = floor(s1), f2 = floor(s2);
    double w0 = s0 - f0, w1 = s1 - f1, w2 = s2 - f2;
    int i0 = (int)f0, i1 = (int)f1, i2 = (int)f2;

    float tq[KVOL];
    #pragma unroll
    for (int q = 0; q < KVOL; q++) tq[q] = 0.0f;

    for (int dz = 0; dz < 2; dz++)
      for (int dy = 0; dy < 2; dy++)
        for (int dx = 0; dx < 2; dx++) {
            int n0 = i0 + dz, n1 = i1 + dy, n2 = i2 + dx;
            bool valid = (n0 >= 0 && n0 < 3 && n1 >= 0 && n1 < 3 && n2 >= 0 && n2 < 3);
            double wt = (dz ? w0 : 1.0 - w0) * (dy ? w1 : 1.0 - w1) * (dx ? w2 : 1.0 - w2);
            int lin = n0 * 9 + n1 * 3 + n2;
            lin = lin < 0 ? 0 : (lin > 26 ? 26 : lin);   // np.clip
            if (valid) tq[lin] += (float)wt;
        }

    for (int i = 0; i < I_CH; i++) {
        const float* wf = w + (o * I_CH + i) * KVOL;
        float acc = 0.0f;
        for (int q = 0; q < KVOL; q++)
            acc = fmaf(tq[q], wf[q], acc);   // f32 fma chain, ascending q
        wrot[((o * KVOL + p) * I_CH + i) * N_ROT + r] = acc;
        if (FULL) {
            wrotT[((size_t)o * N_ROT + r) * 216 + p * 8 + i] = acc;
            ushort hi = f2bf(acc);
            ushort lo = f2bf(acc - bf2f(hi));
            wbf_hi[o * 7168 + (p * 32 + r) * 8 + i] = hi;
            wbf_lo[o * 7168 + (p * 32 + r) * 8 + i] = lo;
        }
    }
    if (FULL && p == 0) {            // zero the pad tap 27 for this (o, r)
        for (int i = 0; i < I_CH; i++) {
            wbf_hi[o * 7168 + ((27 * 32) + r) * 8 + i] = 0;
            wbf_lo[o * 7168 + ((27 * 32) + r) * 8 + i] = 0;
        }
    }
}

// ---------------------------------------------------------------------------
// Kernel 1b: zero-pad + transpose x (NCDHW 40^3) -> xp (NDHWC 42^3) f32.
// ---------------------------------------------------------------------------
__global__ void pad_x(const float* __restrict__ x, float* __restrict__ xp) {
    int idx = blockIdx.x * blockDim.x + threadIdx.x;
    if (idx >= XPAD_ELEMS) return;
    int ci = idx & 7;
    int s  = (idx >> 3) % PSPAT;
    int b  = idx / (8 * PSPAT);
    int xq = s % PDHW;
    int yq = (s / PDHW) % PDHW;
    int zq = s / (PDHW * PDHW);
    float v = 0.0f;
    if (xq >= 1 && xq <= DHW && yq >= 1 && yq <= DHW && zq >= 1 && zq <= DHW)
        v = x[((b * I_CH + ci) * SPATIAL) + ((zq - 1) * DHW + (yq - 1)) * DHW + (xq - 1)];
    xp[idx] = v;
}

// DPP row-rotate (max, min-idx) combine step; CTRL must be a literal.
#define DPP_RED_STEP(CTRL)                                                     \
    {                                                                          \
        float ov = __int_as_float(__builtin_amdgcn_mov_dpp(                    \
            __float_as_int(bval), CTRL, 0xF, 0xF, false));                     \
        int oi = __builtin_amdgcn_mov_dpp(bidx, CTRL, 0xF, 0xF, false);        \
        if (ov > bval || (ov == bval && oi < bidx)) { bval = ov; bidx = oi; }  \
    }

// ---------------------------------------------------------------------------
// Kernel 2: SPLIT-bf16 MFMA screen. R20's verified structure (padded tile,
// DPP row_ror argmax, 6 independent MFMA chains) with the z-tile HALVED:
// 6 staged planes, 4 output z per block, zc in 0..9 -> LDS ~25.5KB ->
// 6 resident blocks/CU; grid = 5*5*10*4*2 = 2000 (R18/R19's crash was
// launching 4000 blocks against this 2000-block decode -> b=2,3 OOB writes).
// Bounds: src plane <= 41 < 42; LDS dst <= 5271 < 5280; A-read <= 10544
// < 10560 bytes; b in {0,1}.
// ---------------------------------------------------------------------------
__global__ __launch_bounds__(256) void mfma_screen(
        const float* __restrict__ xp,
        const ushort* __restrict__ wbf_hi,
        const ushort* __restrict__ wbf_lo,
        float* __restrict__ out,
        int* __restrict__ gcount,
        int* __restrict__ gwork,
        unsigned* __restrict__ gmask) {
    __shared__ __align__(16) ushort xhi[6 * PZS * 8];   // padded tile, bf16 hi
    __shared__ __align__(16) ushort xlo[6 * PZS * 8];   // residual lo
    __shared__ float stab[N_ROT], ctab[N_ROT];
    __shared__ int llist[512];
    __shared__ unsigned lmaskl[512];
    __shared__ int lcnt, lbase;

    int blk = blockIdx.x;
    int tx = blk % 5; blk /= 5;
    int ty = blk % 5; blk /= 5;
    int zc = blk % 10; blk /= 10;     // 10 z-chunks of 4 output planes
    int og = blk % 4; blk /= 4;
    int b  = blk;                     // 0..1 (grid 2000 exactly)

    int lt = threadIdx.x;
    if (lt == 0) lcnt = 0;
    if (lt < N_ROT) {                         // trig LUT: same calls as before
        float ang = (float)lt * (float)(M_PI / 4.0);
        stab[lt] = sinf(ang);
        ctab[lt] = cosf(ang);
    }

    // stage 6x10x10x8 split-bf16 tile ONCE into the PADDED layout
    const float* __restrict__ xpb = xp + (size_t)b * (PSPAT * 8);
    for (int i4 = lt; i4 < 1200; i4 += 256) {
        int e = i4 * 4;
        int pz = e / 800;                     // 0..5
        int rem = e - pz * 800;
        int py = rem / 80;
        int r80 = rem - py * 80;
        int px = r80 >> 3;
        int c4 = r80 & 7;                     // 0 or 4
        const float* src = xpb + (((size_t)(zc * 4 + pz) * PDHW + (ty * 8 + py)) * PDHW
                                  + tx * 8 + px) * 8 + c4;
        float4 v = *(const float4*)src;
        ushort4 h, l2;
        h.x = f2bf(v.x); l2.x = f2bf(v.x - bf2f(h.x));
        h.y = f2bf(v.y); l2.y = f2bf(v.y - bf2f(h.y));
        h.z = f2bf(v.z); l2.z = f2bf(v.z - bf2f(h.z));
        h.w = f2bf(v.w); l2.w = f2bf(v.w - bf2f(h.w));
        int dst = (pz * PZS + py * PYS + px) * 8 + c4;
        *(ushort4*)(xhi + dst) = h;
        *(ushort4*)(xlo + dst) = l2;
    }
    __syncthreads();

    int w = lt >> 6;             // wave 0..3
    int l = lt & 63;
    int g = l >> 4;              // lane quad (16-lane DPP row)
    int c = l & 15;              // B/D column (rotation mod 16)
    int m = l & 15;              // A row (voxel in wave tile)
    int vyl = w * 2 + (m >> 3);  // A-row voxel y within 8x8 tile
    int vxl = m & 7;

    // A-frag byte offsets (dz=0); lane's tap = tg*4+g (tap 27 -> clamp, B=0)
    int offA[7];
    #pragma unroll
    for (int tg = 0; tg < 7; tg++) {
        int tap = tg * 4 + g; if (tap > 26) tap = 26;
        int kz = tap / 9, r9 = tap % 9, ky = r9 / 3, kx = r9 % 3;
        offA[tg] = ((kz * PZS) + (vyl + ky) * PYS + (vxl + kx)) * 16;
    }

    for (int oo = 0; oo < 4; oo++) {
        int o = og * 4 + oo;

        // B fragments hi+lo for this o (tap 27 entries zeroed in wbf)
        bf16x8 Bh[7][2], Bl[7][2];
        #pragma unroll
        for (int tg = 0; tg < 7; tg++)
            #pragma unroll
            for (int t = 0; t < 2; t++) {
                int off = o * 7168 + (((tg * 4 + g) * 32) + t * 16 + c) * 8;
                Bh[tg][t] = *(const bf16x8*)(wbf_hi + off);
                Bl[tg][t] = *(const bf16x8*)(wbf_lo + off);
            }

        #pragma clang loop unroll(disable)
        for (int dz = 0; dz < 4; dz++) {
            // 6 independent accumulator chains, depth 7 each
            f32x4 a0h = {0.f,0.f,0.f,0.f}, a0m = {0.f,0.f,0.f,0.f}, a0l = {0.f,0.f,0.f,0.f};
            f32x4 a1h = {0.f,0.f,0.f,0.f}, a1m = {0.f,0.f,0.f,0.f}, a1l = {0.f,0.f,0.f,0.f};
            #pragma unroll
            for (int tg = 0; tg < 7; tg++) {
                bf16x8 ah = *(const bf16x8*)((const char*)xhi + offA[tg] + dz * (PZS * 16));
                bf16x8 al = *(const bf16x8*)((const char*)xlo + offA[tg] + dz * (PZS * 16));
                a0h = __builtin_amdgcn_mfma_f32_16x16x32_bf16(ah, Bh[tg][0], a0h, 0, 0, 0);
                a0m = __builtin_amdgcn_mfma_f32_16x16x32_bf16(ah, Bl[tg][0], a0m, 0, 0, 0);
                a0l = __builtin_amdgcn_mfma_f32_16x16x32_bf16(al, Bh[tg][0], a0l, 0, 0, 0);
                a1h = __builtin_amdgcn_mfma_f32_16x16x32_bf16(ah, Bh[tg][1], a1h, 0, 0, 0);
                a1m = __builtin_amdgcn_mfma_f32_16x16x32_bf16(ah, Bl[tg][1], a1m, 0, 0, 0);
                a1l = __builtin_amdgcn_mfma_f32_16x16x32_bf16(al, Bh[tg][1], a1l, 0, 0, 0);
            }
            f32x4 acc0 = (a0h + a0m) + a0l;
            f32x4 acc1 = (a1h + a1m) + a1l;

            // per-voxel reduce; voxel m' = g*4+j, lane holds rotations c, c+16
            #pragma unroll
            for (int j = 0; j < 4; j++) {
                float v0 = acc0[j], v1 = acc1[j];
                float bval = (v1 > v0) ? v1 : v0;      // first-max: prefer c
                int   bidx = (v1 > v0) ? c + 16 : c;
                // all-reduce (max, min idx) over the 16-lane DPP row via
                // row_ror:1/2/4/8 (assoc+comm -> same result as butterfly)
                DPP_RED_STEP(0x121)
                DPP_RED_STEP(0x122)
                DPP_RED_STEP(0x124)
                DPP_RED_STEP(0x128)
                unsigned long long bal0 = __ballot(v0 >= bval - MARGIN);
                unsigned long long bal1 = __ballot(v1 >= bval - MARGIN);

                if (c == 0) {
                    unsigned mask = (unsigned)((bal0 >> (g * 16)) & 0xFFFFull)
                                  | ((unsigned)((bal1 >> (g * 16)) & 0xFFFFull) << 16);
                    int cls = bidx & 7;
                    int myflag = (mask & ~(0x01010101u << cls)) != 0;

                    int vq = g * 4 + j;
                    int z  = zc * 4 + dz;
                    int vy = ty * 8 + w * 2 + (vq >> 3);
                    int vx = tx * 8 + (vq & 7);
                    float s_ = bval > 0.f ? bval : 0.f;
                    float sa = stab[bidx], ca = ctab[bidx];
                    int oidx = ((b * O_CH + o) * SPATIAL) + (z * DHW + vy) * DHW + vx;
                    out[oidx]                 = s_ * sa * ca;
                    out[oidx + OUT_PLANE]     = s_ * sa * sa;
                    out[oidx + 2 * OUT_PLANE] = s_ * ca;
                    if (myflag) {
                        int p = atomicAdd(&lcnt, 1);
                        if (p < 512) { llist[p] = oidx; lmaskl[p] = mask; }
                    }
                }
            }
        }
    }
    __syncthreads();
    int n = lcnt < 512 ? lcnt : 512;
    if (lt == 0 && n > 0) lbase = atomicAdd(gcount, n);
    __syncthreads();
    for (int i = lt; i < n; i += 256) {
        gwork[lbase + i] = llist[i];
        gmask[lbase + i] = lmaskl[i];
    }
}

// ---------------------------------------------------------------------------
// Kernel 3: exact fixup for flagged voxels — CANDIDATE ROTATIONS ONLY.
// Chains bit-identical to the verified R4-R20 reference ordering.
// ---------------------------------------------------------------------------
__global__ __launch_bounds__(256) void fixup(
        const float* __restrict__ xp,
        const float* __restrict__ wrotT,
        const int* __restrict__ gcount,
        const int* __restrict__ gwork,
        const unsigned* __restrict__ gmask,
        float* __restrict__ out) {
    int n = *gcount;
    if (n > WORK_CAP) n = WORK_CAP;
    for (int i = blockIdx.x * 256 + threadIdx.x; i < n; i += gridDim.x * 256) {
        int oidx = gwork[i];
        unsigned mask = gmask[i];
        int vox = oidx % SPATIAL;
        int bo  = oidx / SPATIAL;
        int b = bo >> 4, o = bo & 15;
        int z = vox / 1600;
        int rem = vox - z * 1600;
        int vy = rem / 40, vx = rem - (rem / 40) * 40;

        const float* __restrict__ xpb = xp + (size_t)b * (PSPAT * 8);
        const float* __restrict__ wr  = wrotT + (size_t)o * N_ROT * 216;

        float best = 0.f; int bi = 0; bool first = true;
        while (mask) {
            int r = __ffs(mask) - 1;
            mask &= mask - 1;
            const float* wrr = wr + r * 216;
            float acc = 0.f;
            for (int k = 0; k < KVOL; k++) {
                int kz = k / 9, r9 = k % 9, ky = r9 / 3, kx = r9 % 3;
                const float* xv = xpb + (((size_t)(z + kz) * PDHW + (vy + ky)) * PDHW
                                         + (vx + kx)) * 8;
                float4 xa = *(const float4*)xv;
                float4 xb = *(const float4*)(xv + 4);
                float4 wa = *(const float4*)(wrr + k * 8);
                float4 wb = *(const float4*)(wrr + k * 8 + 4);
                acc = fmaf(xa.x, wa.x, acc);
                acc = fmaf(xa.y, wa.y, acc);
                acc = fmaf(xa.z, wa.z, acc);
                acc = fmaf(xa.w, wa.w, acc);
                acc = fmaf(xb.x, wb.x, acc);
                acc = fmaf(xb.y, wb.y, acc);
                acc = fmaf(xb.z, wb.z, acc);
                acc = fmaf(xb.w, wb.w, acc);
            }
            if (first || acc > best) { best = acc; bi = r; first = false; }
        }
        float s = best > 0.f ? best : 0.f;
        float ang = (float)bi * (float)(M_PI / 4.0);
        float sa = sinf(ang), ca = cosf(ang);
        out[oidx]                 = s * sa * ca;
        out[oidx + OUT_PLANE]     = s * sa * sa;
        out[oidx + 2 * OUT_PLANE] = s * ca;
    }
}

// ---------------------------------------------------------------------------
// Fallback (ws too small): exact scalar conv, bounds-checked NCDHW (R7-style).
// ---------------------------------------------------------------------------
__global__ __launch_bounds__(256, 4) void conv_fallback(
        const float* __restrict__ xg,
        const float* __restrict__ wrot,
        float* __restrict__ out) {
    int blk = blockIdx.x;
    int tx = blk % 5; blk /= 5;
    int ty = blk % 5; blk /= 5;
    int tz = blk % 5; blk /= 5;
    int o  = blk % O_CH; blk /= O_CH;
    int b  = blk;

    int lt = threadIdx.x;
    int lx = lt & 7;
    int ly = (lt >> 3) & 7;
    int lz = lt >> 6;
    int xx = tx * 8 + lx;
    int yy = ty * 8 + ly;
    int zb = tz * 8 + lz * 2;

    float acc0[N_ROT], acc1[N_ROT];
    #pragma unroll
    for (int r = 0; r < N_ROT; r++) { acc0[r] = 0.0f; acc1[r] = 0.0f; }

    const float* __restrict__ wo = wrot + o * (KVOL * I_CH * N_ROT);
    const float* __restrict__ xb = xg + (size_t)b * I_CH * SPATIAL;
    #pragma clang loop unroll(disable)
    for (int k = 0; k < KVOL; k++) {
        int kz = k / 9, ky = (k / 3) % 3, kx = k % 3;
        int z0 = zb + kz - 1;
        int yv = yy + ky - 1;
        int xv = xx + kx - 1;
        bool xyok = ((unsigned)yv < DHW) && ((unsigned)xv < DHW);
        bool ok0 = xyok && ((unsigned)z0 < DHW);
        bool ok1 = xyok && ((unsigned)(z0 + 1) < DHW);
        int sbase = (z0 * DHW + yv) * DHW + xv;
        const float* __restrict__ wk = wo + k * (I_CH * N_ROT);
        #pragma clang loop unroll(disable)
        for (int ci = 0; ci < I_CH; ci++) {
            const float* xc = xb + ci * SPATIAL;
            float x0 = ok0 ? xc[sbase] : 0.0f;
            float x1 = ok1 ? xc[sbase + DHW * DHW] : 0.0f;
            const float* __restrict__ wp = wk + ci * N_ROT;
            #pragma unroll
            for (int r = 0; r < N_ROT; r++) {
                float wv = wp[r];
                acc0[r] = fmaf(x0, wv, acc0[r]);
                acc1[r] = fmaf(x1, wv, acc1[r]);
            }
        }
    }
    #pragma unroll
    for (int v = 0; v < 2; v++) {
        const float* a = v ? acc1 : acc0;
        float best = a[0]; int bi = 0;
        #pragma unroll
        for (int r = 1; r < N_ROT; r++)
            if (a[r] > best) { best = a[r]; bi = r; }
        float s = best > 0.0f ? best : 0.0f;
        float ang = (float)bi * (float)(M_PI / 4.0);
        float sa = sinf(ang), ca = cosf(ang);
        int oidx = ((b * O_CH + o) * SPATIAL) + ((zb + v) * DHW + yy) * DHW + xx;
        out[oidx]                 = s * sa * ca;
        out[oidx + OUT_PLANE]     = s * sa * sa;
        out[oidx + 2 * OUT_PLANE] = s * ca;
    }
}

extern "C" void kernel_launch(void* const* d_in, const int* in_sizes, int n_in,
                              void* d_out, int out_size, void* d_ws, size_t ws_size,
                              hipStream_t stream) {
    const float* x = (const float*)d_in[0];      // [2,8,40,40,40]
    const float* w = (const float*)d_in[1];      // [16,8,3,3,3]
    float* out = (float*)d_out;
    char* ws = (char*)d_ws;

    float*    wrot   = (float*)ws;                   //  442368 B
    float*    xp     = (float*)(ws + 442368);        // 4741632 B
    float*    wrotT  = (float*)(ws + 5184000);       //  442368 B
    ushort*   wbf_hi = (ushort*)(ws + 5626368);      //  229376 B
    ushort*   wbf_lo = (ushort*)(ws + 5855744);      //  229376 B
    int*      gcount = (int*)(ws + 6085120);         //     256 B
    int*      gwork  = (int*)(ws + 6085376);         // WORK_CAP*4
    unsigned* gmask  = (unsigned*)(ws + 6085376 + (size_t)WORK_CAP * 4);
    const size_t need = 6085376 + (size_t)WORK_CAP * 8;

    int bw_grid = (N_ROT * KVOL * O_CH + 255) / 256;   // 54 blocks

    if (ws_size >= need) {
        build_wrot<true><<<bw_grid, 256, 0, stream>>>(w, wrot, wrotT, wbf_hi, wbf_lo, gcount);
        pad_x<<<(XPAD_ELEMS + 255) / 256, 256, 0, stream>>>(x, xp);
        // grid: 5tx * 5ty * 10zc * 4og * 2b = 2000 blocks (decode matches!)
        mfma_screen<<<2000, 256, 0, stream>>>(xp, wbf_hi, wbf_lo, out, gcount, gwork, gmask);
        fixup<<<1024, 256, 0, stream>>>(xp, wrotT, gcount, gwork, gmask, out);
    } else {
        build_wrot<false><<<bw_grid, 256, 0, stream>>>(w, wrot, nullptr, nullptr, nullptr, nullptr);
        conv_fallback<<<4000, 256, 0, stream>>>(x, wrot, out);
    }
}

// Round 22
// 199.811 us; speedup vs baseline: 1.0664x; 1.0664x over previous
//
#include <hip/hip_runtime.h>
#include <hip/hip_bf16.h>
#include <math.h>

// Problem constants
#define N_ROT 32      // 8 inclinations x 4 azimuths
#define O_CH 16
#define I_CH 8
#define KVOL 27
#define DHW 40
#define SPATIAL (DHW*DHW*DHW)        // 64000
#define OUT_PLANE (2*O_CH*SPATIAL)   // 2048000 elements per output tensor
#define PDHW 42
#define PSPAT (PDHW*PDHW*PDHW)       // 74088
#define WROT_ELEMS (O_CH*KVOL*I_CH*N_ROT)   // 110592 f32
#define XPAD_ELEMS (2*PSPAT*I_CH)           // 1185408 f32 (NDHWC padded)
// split-bf16 screen error ~3e-5 worst-case realistic; margin = 2e-3 (>>10x)
#define MARGIN 2.0e-3f
#define WORK_CAP 2048000
// padded LDS x-tile geometry (16B px units): py stride 11, pz stride 110
#define PYS 11
#define PZS 110

typedef __attribute__((ext_vector_type(8))) short bf16x8;
typedef __attribute__((ext_vector_type(4))) float f32x4;

__device__ __forceinline__ ushort f2bf(float v) {
    union { __hip_bfloat16 h; ushort u; } cv;
    cv.h = __float2bfloat16(v);      // RNE
    return cv.u;
}
__device__ __forceinline__ float bf2f(ushort u) {
    union { unsigned u32; float f; } cv;
    cv.u32 = ((unsigned)u) << 16;
    return cv.f;
}

// ---------------------------------------------------------------------------
// Kernel 1: rotated weights, parallelized over (o, r, p) — verified in R20.
// Per-(o,i,r,p) contraction chain UNCHANGED from passing R4-R20 kernels
// (bit pattern load-bearing).
// ---------------------------------------------------------------------------
template<bool FULL>
__global__ void build_wrot(const float* __restrict__ w, float* __restrict__ wrot,
                           float* __restrict__ wrotT, ushort* __restrict__ wbf_hi,
                           ushort* __restrict__ wbf_lo, int* __restrict__ gcount) {
    int tid = blockIdx.x * blockDim.x + threadIdx.x;
    if (FULL && tid == 0) *gcount = 0;
    if (tid >= N_ROT * KVOL * O_CH) return;
    int o  = tid / (N_ROT * KVOL);
    int rp = tid % (N_ROT * KVOL);
    int r = rp / KVOL, p = rp % KVOL;
    int th = r / 4, ph = r % 4;
    double theta = ((double)th * 22.5) * (M_PI / 180.0);   // np.deg2rad
    double phi   = ((double)ph * 90.0) * (M_PI / 180.0);
    double ct = cos(theta), st = sin(theta);
    double cp = cos(phi),   sp = sin(phi);
    double R00 = cp*ct, R01 = -sp, R02 = cp*st;
    double R10 = sp*ct, R11 =  cp, R12 = sp*st;
    double R20 = -st,   R21 = 0.0, R22 = ct;
    double d0 = (double)(p / 9) - 1.0;
    double d1 = (double)((p / 3) % 3) - 1.0;
    double d2 = (double)(p % 3) - 1.0;
    double s0 = d0*R00 + d1*R10 + d2*R20 + 1.0;
    double s1 = d0*R01 + d1*R11 + d2*R21 + 1.0;
    double s2 = d0*R02 + d1*R12 + d2*R22 + 1.0;
    double f0 = floor(s0), f1 = floor(s1), f2 = floor(s2);
    double w0 = s0 - f0, w1 = s1 - f1, w2 = s2 - f2;
    int i0 = (int)f0, i1 = (int)f1, i2 = (int)f2;

    float tq[KVOL];
    #pragma unroll
    for (int q = 0; q < KVOL; q++) tq[q] = 0.0f;

    for (int dz = 0; dz < 2; dz++)
      for (int dy = 0; dy < 2; dy++)
        for (int dx = 0; dx < 2; dx++) {
            int n0 = i0 + dz, n1 = i1 + dy, n2 = i2 + dx;
            bool valid = (n0 >= 0 && n0 < 3 && n1 >= 0 && n1 < 3 && n2 >= 0 && n2 < 3);
            double wt = (dz ? w0 : 1.0 - w0) * (dy ? w1 : 1.0 - w1) * (dx ? w2 : 1.0 - w2);
            int lin = n0 * 9 + n1 * 3 + n2;
            lin = lin < 0 ? 0 : (lin > 26 ? 26 : lin);   // np.clip
            if (valid) tq[lin] += (float)wt;
        }

    for (int i = 0; i < I_CH; i++) {
        const float* wf = w + (o * I_CH + i) * KVOL;
        float acc = 0.0f;
        for (int q = 0; q < KVOL; q++)
            acc = fmaf(tq[q], wf[q], acc);   // f32 fma chain, ascending q
        wrot[((o * KVOL + p) * I_CH + i) * N_ROT + r] = acc;
        if (FULL) {
            wrotT[((size_t)o * N_ROT + r) * 216 + p * 8 + i] = acc;
            ushort hi = f2bf(acc);
            ushort lo = f2bf(acc - bf2f(hi));
            wbf_hi[o * 7168 + (p * 32 + r) * 8 + i] = hi;
            wbf_lo[o * 7168 + (p * 32 + r) * 8 + i] = lo;
        }
    }
    if (FULL && p == 0) {            // zero the pad tap 27 for this (o, r)
        for (int i = 0; i < I_CH; i++) {
            wbf_hi[o * 7168 + ((27 * 32) + r) * 8 + i] = 0;
            wbf_lo[o * 7168 + ((27 * 32) + r) * 8 + i] = 0;
        }
    }
}

// ---------------------------------------------------------------------------
// Kernel 1b: zero-pad + transpose x (NCDHW 40^3) -> xp (NDHWC 42^3) f32.
// ---------------------------------------------------------------------------
__global__ void pad_x(const float* __restrict__ x, float* __restrict__ xp) {
    int idx = blockIdx.x * blockDim.x + threadIdx.x;
    if (idx >= XPAD_ELEMS) return;
    int ci = idx & 7;
    int s  = (idx >> 3) % PSPAT;
    int b  = idx / (8 * PSPAT);
    int xq = s % PDHW;
    int yq = (s / PDHW) % PDHW;
    int zq = s / (PDHW * PDHW);
    float v = 0.0f;
    if (xq >= 1 && xq <= DHW && yq >= 1 && yq <= DHW && zq >= 1 && zq <= DHW)
        v = x[((b * I_CH + ci) * SPATIAL) + ((zq - 1) * DHW + (yq - 1)) * DHW + (xq - 1)];
    xp[idx] = v;
}

// DPP row-rotate (max, min-idx) combine step; CTRL must be a literal.
#define DPP_RED_STEP(CTRL)                                                     \
    {                                                                          \
        float ov = __int_as_float(__builtin_amdgcn_mov_dpp(                    \
            __float_as_int(bval), CTRL, 0xF, 0xF, false));                     \
        int oi = __builtin_amdgcn_mov_dpp(bidx, CTRL, 0xF, 0xF, false);        \
        if (ov > bval || (ov == bval && oi < bidx)) { bval = ov; bidx = oi; }  \
    }

// ---------------------------------------------------------------------------
// Kernel 2: SPLIT-bf16 MFMA screen — the R20 configuration (best measured:
// 199.9 us total, screen 158.9 us). Padded x-tile (PYS/PZS), DPP row_ror
// argmax reduce, 6 independent MFMA chains, 10-plane tile, grid 1000.
// R21's z-halving regressed (occupancy is chain-limited, not LDS-limited),
// so this reverts to the optimum.
// ---------------------------------------------------------------------------
__global__ __launch_bounds__(256) void mfma_screen(
        const float* __restrict__ xp,
        const ushort* __restrict__ wbf_hi,
        const ushort* __restrict__ wbf_lo,
        float* __restrict__ out,
        int* __restrict__ gcount,
        int* __restrict__ gwork,
        unsigned* __restrict__ gmask) {
    __shared__ __align__(16) ushort xhi[10 * PZS * 8];   // padded tile, bf16 hi
    __shared__ __align__(16) ushort xlo[10 * PZS * 8];   // residual lo
    __shared__ float stab[N_ROT], ctab[N_ROT];
    __shared__ int llist[512];
    __shared__ unsigned lmaskl[512];
    __shared__ int lcnt, lbase;

    int blk = blockIdx.x;
    int tx = blk % 5; blk /= 5;
    int ty = blk % 5; blk /= 5;
    int zc = blk % 5; blk /= 5;
    int og = blk % 4; blk /= 4;
    int b  = blk;

    int lt = threadIdx.x;
    if (lt == 0) lcnt = 0;
    if (lt < N_ROT) {                         // trig LUT: same calls as before
        float ang = (float)lt * (float)(M_PI / 4.0);
        stab[lt] = sinf(ang);
        ctab[lt] = cosf(ang);
    }

    // stage 10x10x10x8 split-bf16 tile ONCE into the PADDED layout
    const float* __restrict__ xpb = xp + (size_t)b * (PSPAT * 8);
    for (int i4 = lt; i4 < 2000; i4 += 256) {
        int e = i4 * 4;
        int pz = e / 800;
        int rem = e - pz * 800;
        int py = rem / 80;
        int r80 = rem - py * 80;
        int px = r80 >> 3;
        int c4 = r80 & 7;                     // 0 or 4
        const float* src = xpb + (((size_t)(zc * 8 + pz) * PDHW + (ty * 8 + py)) * PDHW
                                  + tx * 8 + px) * 8 + c4;
        float4 v = *(const float4*)src;
        ushort4 h, l2;
        h.x = f2bf(v.x); l2.x = f2bf(v.x - bf2f(h.x));
        h.y = f2bf(v.y); l2.y = f2bf(v.y - bf2f(h.y));
        h.z = f2bf(v.z); l2.z = f2bf(v.z - bf2f(h.z));
        h.w = f2bf(v.w); l2.w = f2bf(v.w - bf2f(h.w));
        int dst = (pz * PZS + py * PYS + px) * 8 + c4;
        *(ushort4*)(xhi + dst) = h;
        *(ushort4*)(xlo + dst) = l2;
    }
    __syncthreads();

    int w = lt >> 6;             // wave 0..3
    int l = lt & 63;
    int g = l >> 4;              // lane quad (16-lane DPP row)
    int c = l & 15;              // B/D column (rotation mod 16)
    int m = l & 15;              // A row (voxel in wave tile)
    int vyl = w * 2 + (m >> 3);  // A-row voxel y within 8x8 tile
    int vxl = m & 7;

    // A-frag byte offsets (dz=0); lane's tap = tg*4+g (tap 27 -> clamp, B=0)
    int offA[7];
    #pragma unroll
    for (int tg = 0; tg < 7; tg++) {
        int tap = tg * 4 + g; if (tap > 26) tap = 26;
        int kz = tap / 9, r9 = tap % 9, ky = r9 / 3, kx = r9 % 3;
        offA[tg] = ((kz * PZS) + (vyl + ky) * PYS + (vxl + kx)) * 16;
    }

    for (int oo = 0; oo < 4; oo++) {
        int o = og * 4 + oo;

        // B fragments hi+lo for this o (tap 27 entries zeroed in wbf)
        bf16x8 Bh[7][2], Bl[7][2];
        #pragma unroll
        for (int tg = 0; tg < 7; tg++)
            #pragma unroll
            for (int t = 0; t < 2; t++) {
                int off = o * 7168 + (((tg * 4 + g) * 32) + t * 16 + c) * 8;
                Bh[tg][t] = *(const bf16x8*)(wbf_hi + off);
                Bl[tg][t] = *(const bf16x8*)(wbf_lo + off);
            }

        #pragma clang loop unroll(disable)
        for (int dz = 0; dz < 8; dz++) {
            // 6 independent accumulator chains, depth 7 each
            f32x4 a0h = {0.f,0.f,0.f,0.f}, a0m = {0.f,0.f,0.f,0.f}, a0l = {0.f,0.f,0.f,0.f};
            f32x4 a1h = {0.f,0.f,0.f,0.f}, a1m = {0.f,0.f,0.f,0.f}, a1l = {0.f,0.f,0.f,0.f};
            #pragma unroll
            for (int tg = 0; tg < 7; tg++) {
                bf16x8 ah = *(const bf16x8*)((const char*)xhi + offA[tg] + dz * (PZS * 16));
                bf16x8 al = *(const bf16x8*)((const char*)xlo + offA[tg] + dz * (PZS * 16));
                a0h = __builtin_amdgcn_mfma_f32_16x16x32_bf16(ah, Bh[tg][0], a0h, 0, 0, 0);
                a0m = __builtin_amdgcn_mfma_f32_16x16x32_bf16(ah, Bl[tg][0], a0m, 0, 0, 0);
                a0l = __builtin_amdgcn_mfma_f32_16x16x32_bf16(al, Bh[tg][0], a0l, 0, 0, 0);
                a1h = __builtin_amdgcn_mfma_f32_16x16x32_bf16(ah, Bh[tg][1], a1h, 0, 0, 0);
                a1m = __builtin_amdgcn_mfma_f32_16x16x32_bf16(ah, Bl[tg][1], a1m, 0, 0, 0);
                a1l = __builtin_amdgcn_mfma_f32_16x16x32_bf16(al, Bh[tg][1], a1l, 0, 0, 0);
            }
            f32x4 acc0 = (a0h + a0m) + a0l;
            f32x4 acc1 = (a1h + a1m) + a1l;

            // per-voxel reduce; voxel m' = g*4+j, lane holds rotations c, c+16
            #pragma unroll
            for (int j = 0; j < 4; j++) {
                float v0 = acc0[j], v1 = acc1[j];
                float bval = (v1 > v0) ? v1 : v0;      // first-max: prefer c
                int   bidx = (v1 > v0) ? c + 16 : c;
                // all-reduce (max, min idx) over the 16-lane DPP row via
                // row_ror:1/2/4/8 (assoc+comm -> same result as butterfly)
                DPP_RED_STEP(0x121)
                DPP_RED_STEP(0x122)
                DPP_RED_STEP(0x124)
                DPP_RED_STEP(0x128)
                unsigned long long bal0 = __ballot(v0 >= bval - MARGIN);
                unsigned long long bal1 = __ballot(v1 >= bval - MARGIN);

                if (c == 0) {
                    unsigned mask = (unsigned)((bal0 >> (g * 16)) & 0xFFFFull)
                                  | ((unsigned)((bal1 >> (g * 16)) & 0xFFFFull) << 16);
                    int cls = bidx & 7;
                    int myflag = (mask & ~(0x01010101u << cls)) != 0;

                    int vq = g * 4 + j;
                    int z  = zc * 8 + dz;
                    int vy = ty * 8 + w * 2 + (vq >> 3);
                    int vx = tx * 8 + (vq & 7);
                    float s_ = bval > 0.f ? bval : 0.f;
                    float sa = stab[bidx], ca = ctab[bidx];
                    int oidx = ((b * O_CH + o) * SPATIAL) + (z * DHW + vy) * DHW + vx;
                    out[oidx]                 = s_ * sa * ca;
                    out[oidx + OUT_PLANE]     = s_ * sa * sa;
                    out[oidx + 2 * OUT_PLANE] = s_ * ca;
                    if (myflag) {
                        int p = atomicAdd(&lcnt, 1);
                        if (p < 512) { llist[p] = oidx; lmaskl[p] = mask; }
                    }
                }
            }
        }
    }
    __syncthreads();
    int n = lcnt < 512 ? lcnt : 512;
    if (lt == 0 && n > 0) lbase = atomicAdd(gcount, n);
    __syncthreads();
    for (int i = lt; i < n; i += 256) {
        gwork[lbase + i] = llist[i];
        gmask[lbase + i] = lmaskl[i];
    }
}

// ---------------------------------------------------------------------------
// Kernel 3: exact fixup for flagged voxels — CANDIDATE ROTATIONS ONLY.
// Chains bit-identical to the verified R4-R20 reference ordering.
// ---------------------------------------------------------------------------
__global__ __launch_bounds__(256) void fixup(
        const float* __restrict__ xp,
        const float* __restrict__ wrotT,
        const int* __restrict__ gcount,
        const int* __restrict__ gwork,
        const unsigned* __restrict__ gmask,
        float* __restrict__ out) {
    int n = *gcount;
    if (n > WORK_CAP) n = WORK_CAP;
    for (int i = blockIdx.x * 256 + threadIdx.x; i < n; i += gridDim.x * 256) {
        int oidx = gwork[i];
        unsigned mask = gmask[i];
        int vox = oidx % SPATIAL;
        int bo  = oidx / SPATIAL;
        int b = bo >> 4, o = bo & 15;
        int z = vox / 1600;
        int rem = vox - z * 1600;
        int vy = rem / 40, vx = rem - (rem / 40) * 40;

        const float* __restrict__ xpb = xp + (size_t)b * (PSPAT * 8);
        const float* __restrict__ wr  = wrotT + (size_t)o * N_ROT * 216;

        float best = 0.f; int bi = 0; bool first = true;
        while (mask) {
            int r = __ffs(mask) - 1;
            mask &= mask - 1;
            const float* wrr = wr + r * 216;
            float acc = 0.f;
            for (int k = 0; k < KVOL; k++) {
                int kz = k / 9, r9 = k % 9, ky = r9 / 3, kx = r9 % 3;
                const float* xv = xpb + (((size_t)(z + kz) * PDHW + (vy + ky)) * PDHW
                                         + (vx + kx)) * 8;
                float4 xa = *(const float4*)xv;
                float4 xb = *(const float4*)(xv + 4);
                float4 wa = *(const float4*)(wrr + k * 8);
                float4 wb = *(const float4*)(wrr + k * 8 + 4);
                acc = fmaf(xa.x, wa.x, acc);
                acc = fmaf(xa.y, wa.y, acc);
                acc = fmaf(xa.z, wa.z, acc);
                acc = fmaf(xa.w, wa.w, acc);
                acc = fmaf(xb.x, wb.x, acc);
                acc = fmaf(xb.y, wb.y, acc);
                acc = fmaf(xb.z, wb.z, acc);
                acc = fmaf(xb.w, wb.w, acc);
            }
            if (first || acc > best) { best = acc; bi = r; first = false; }
        }
        float s = best > 0.f ? best : 0.f;
        float ang = (float)bi * (float)(M_PI / 4.0);
        float sa = sinf(ang), ca = cosf(ang);
        out[oidx]                 = s * sa * ca;
        out[oidx + OUT_PLANE]     = s * sa * sa;
        out[oidx + 2 * OUT_PLANE] = s * ca;
    }
}

// ---------------------------------------------------------------------------
// Fallback (ws too small): exact scalar conv, bounds-checked NCDHW (R7-style).
// ---------------------------------------------------------------------------
__global__ __launch_bounds__(256, 4) void conv_fallback(
        const float* __restrict__ xg,
        const float* __restrict__ wrot,
        float* __restrict__ out) {
    int blk = blockIdx.x;
    int tx = blk % 5; blk /= 5;
    int ty = blk % 5; blk /= 5;
    int tz = blk % 5; blk /= 5;
    int o  = blk % O_CH; blk /= O_CH;
    int b  = blk;

    int lt = threadIdx.x;
    int lx = lt & 7;
    int ly = (lt >> 3) & 7;
    int lz = lt >> 6;
    int xx = tx * 8 + lx;
    int yy = ty * 8 + ly;
    int zb = tz * 8 + lz * 2;

    float acc0[N_ROT], acc1[N_ROT];
    #pragma unroll
    for (int r = 0; r < N_ROT; r++) { acc0[r] = 0.0f; acc1[r] = 0.0f; }

    const float* __restrict__ wo = wrot + o * (KVOL * I_CH * N_ROT);
    const float* __restrict__ xb = xg + (size_t)b * I_CH * SPATIAL;
    #pragma clang loop unroll(disable)
    for (int k = 0; k < KVOL; k++) {
        int kz = k / 9, ky = (k / 3) % 3, kx = k % 3;
        int z0 = zb + kz - 1;
        int yv = yy + ky - 1;
        int xv = xx + kx - 1;
        bool xyok = ((unsigned)yv < DHW) && ((unsigned)xv < DHW);
        bool ok0 = xyok && ((unsigned)z0 < DHW);
        bool ok1 = xyok && ((unsigned)(z0 + 1) < DHW);
        int sbase = (z0 * DHW + yv) * DHW + xv;
        const float* __restrict__ wk = wo + k * (I_CH * N_ROT);
        #pragma clang loop unroll(disable)
        for (int ci = 0; ci < I_CH; ci++) {
            const float* xc = xb + ci * SPATIAL;
            float x0 = ok0 ? xc[sbase] : 0.0f;
            float x1 = ok1 ? xc[sbase + DHW * DHW] : 0.0f;
            const float* __restrict__ wp = wk + ci * N_ROT;
            #pragma unroll
            for (int r = 0; r < N_ROT; r++) {
                float wv = wp[r];
                acc0[r] = fmaf(x0, wv, acc0[r]);
                acc1[r] = fmaf(x1, wv, acc1[r]);
            }
        }
    }
    #pragma unroll
    for (int v = 0; v < 2; v++) {
        const float* a = v ? acc1 : acc0;
        float best = a[0]; int bi = 0;
        #pragma unroll
        for (int r = 1; r < N_ROT; r++)
            if (a[r] > best) { best = a[r]; bi = r; }
        float s = best > 0.0f ? best : 0.0f;
        float ang = (float)bi * (float)(M_PI / 4.0);
        float sa = sinf(ang), ca = cosf(ang);
        int oidx = ((b * O_CH + o) * SPATIAL) + ((zb + v) * DHW + yy) * DHW + xx;
        out[oidx]                 = s * sa * ca;
        out[oidx + OUT_PLANE]     = s * sa * sa;
        out[oidx + 2 * OUT_PLANE] = s * ca;
    }
}

extern "C" void kernel_launch(void* const* d_in, const int* in_sizes, int n_in,
                              void* d_out, int out_size, void* d_ws, size_t ws_size,
                              hipStream_t stream) {
    const float* x = (const float*)d_in[0];      // [2,8,40,40,40]
    const float* w = (const float*)d_in[1];      // [16,8,3,3,3]
    float* out = (float*)d_out;
    char* ws = (char*)d_ws;

    float*    wrot   = (float*)ws;                   //  442368 B
    float*    xp     = (float*)(ws + 442368);        // 4741632 B
    float*    wrotT  = (float*)(ws + 5184000);       //  442368 B
    ushort*   wbf_hi = (ushort*)(ws + 5626368);      //  229376 B
    ushort*   wbf_lo = (ushort*)(ws + 5855744);      //  229376 B
    int*      gcount = (int*)(ws + 6085120);         //     256 B
    int*      gwork  = (int*)(ws + 6085376);         // WORK_CAP*4
    unsigned* gmask  = (unsigned*)(ws + 6085376 + (size_t)WORK_CAP * 4);
    const size_t need = 6085376 + (size_t)WORK_CAP * 8;

    int bw_grid = (N_ROT * KVOL * O_CH + 255) / 256;   // 54 blocks

    if (ws_size >= need) {
        build_wrot<true><<<bw_grid, 256, 0, stream>>>(w, wrot, wrotT, wbf_hi, wbf_lo, gcount);
        pad_x<<<(XPAD_ELEMS + 255) / 256, 256, 0, stream>>>(x, xp);
        // grid: 5tx * 5ty * 5zc * 4og * 2b = 1000 blocks (~4/CU)
        mfma_screen<<<1000, 256, 0, stream>>>(xp, wbf_hi, wbf_lo, out, gcount, gwork, gmask);
        fixup<<<1024, 256, 0, stream>>>(xp, wrotT, gcount, gwork, gmask, out);
    } else {
        build_wrot<false><<<bw_grid, 256, 0, stream>>>(w, wrot, nullptr, nullptr, nullptr, nullptr);
        conv_fallback<<<4000, 256, 0, stream>>>(x, wrot, out);
    }
}